// Round 2
// baseline (356.487 us; speedup 1.0000x reference)
//
#include <hip/hip_runtime.h>
#include <hip/hip_bf16.h>
#include <math.h>

// B=2, L=2048, D=1024, H=16, Dh=64. M = B*L = 4096.
// Pipeline: gemm<0> (x @ w_qkv + RoPE -> q,k,v bf16 [B,H,L,Dh] in ws)
//           attn    (flash attention -> attn_out bf16 [B,L,D] in ws)
//           gemm<1> (attn_out @ w_proj -> f32 d_out)

#define BM 128
#define BN 128
#define BK 32
#define LDK 40   // padded LDS row stride in bf16 elems (80B, 16B-aligned rows)

typedef __attribute__((ext_vector_type(8))) short bf16x8;
typedef __attribute__((ext_vector_type(4))) float f32x4;

__device__ __forceinline__ unsigned short f2bf(float f) {
    union { float f; unsigned int u; } v; v.f = f;
    unsigned int u = v.u;
    return (unsigned short)((u + 0x7FFFu + ((u >> 16) & 1u)) >> 16);
}

// MODE 0: A = f32 x[M,K], B = f32 w_qkv[K, N=3072]; epilogue: RoPE, scatter q/k/v bf16 [B,H,L,Dh]
// MODE 1: A = bf16 attn_out[M,K], B = f32 w_proj[K,N]; epilogue: f32 C[M,N]
template<int MODE>
__global__ __launch_bounds__(256) void gemm_kernel(
    const void* __restrict__ Aptr, const float* __restrict__ Bptr,
    unsigned short* __restrict__ qb, unsigned short* __restrict__ kb,
    unsigned short* __restrict__ vb, float* __restrict__ Cout,
    int M, int N, int K)
{
    __shared__ __align__(16) unsigned short As[BM][LDK];
    __shared__ __align__(16) unsigned short Bs[BN][LDK];
    int tid = threadIdx.x;
    int wid = tid >> 6, lane = tid & 63, lr = lane & 15, lg = lane >> 4;
    int wm = (wid >> 1) * 64, wn = (wid & 1) * 64;
    int row0 = blockIdx.y * BM, col0 = blockIdx.x * BN;

    f32x4 acc[4][4];
    for (int m = 0; m < 4; ++m)
        for (int n = 0; n < 4; ++n)
            for (int i = 0; i < 4; ++i) acc[m][n][i] = 0.0f;

    for (int k0 = 0; k0 < K; k0 += BK) {
        // ---- stage A tile [BM][BK] as bf16, k-contiguous ----
        if (MODE == 0) {
            const float* A = (const float*)Aptr;
            #pragma unroll
            for (int i = 0; i < 4; ++i) {
                int idx = tid + 256 * i;          // 0..1023
                int r = idx >> 3, c = (idx & 7) * 4;
                float4 f = *(const float4*)(A + (size_t)(row0 + r) * K + k0 + c);
                ushort4 hh;
                hh.x = f2bf(f.x); hh.y = f2bf(f.y); hh.z = f2bf(f.z); hh.w = f2bf(f.w);
                *(ushort4*)(&As[r][c]) = hh;
            }
        } else {
            const unsigned short* A = (const unsigned short*)Aptr;
            #pragma unroll
            for (int i = 0; i < 2; ++i) {
                int idx = tid + 256 * i;          // 0..511
                int r = idx >> 2, c = (idx & 3) * 8;
                *(float4*)(&As[r][c]) = *(const float4*)(A + (size_t)(row0 + r) * K + k0 + c);
            }
        }
        // ---- stage B tile transposed: Bs[n][k] (B^T layout) ----
        #pragma unroll
        for (int i = 0; i < 4; ++i) {
            int idx = tid + 256 * i;              // 0..1023
            int kk = idx >> 5, c = (idx & 31) * 4;
            float4 f = *(const float4*)(Bptr + (size_t)(k0 + kk) * N + col0 + c);
            Bs[c + 0][kk] = f2bf(f.x);
            Bs[c + 1][kk] = f2bf(f.y);
            Bs[c + 2][kk] = f2bf(f.z);
            Bs[c + 3][kk] = f2bf(f.w);
        }
        __syncthreads();

        bf16x8 af[4], bfr[4];
        #pragma unroll
        for (int m = 0; m < 4; ++m) af[m] = *(const bf16x8*)(&As[wm + m * 16 + lr][lg * 8]);
        #pragma unroll
        for (int n = 0; n < 4; ++n) bfr[n] = *(const bf16x8*)(&Bs[wn + n * 16 + lr][lg * 8]);
        #pragma unroll
        for (int m = 0; m < 4; ++m)
            #pragma unroll
            for (int n = 0; n < 4; ++n)
                acc[m][n] = __builtin_amdgcn_mfma_f32_16x16x32_bf16(af[m], bfr[n], acc[m][n], 0, 0, 0);
        __syncthreads();
    }

    // ---- epilogue ----
    if (MODE == 1) {
        #pragma unroll
        for (int m = 0; m < 4; ++m)
            #pragma unroll
            for (int reg = 0; reg < 4; ++reg) {
                int grow = row0 + wm + m * 16 + lg * 4 + reg;
                #pragma unroll
                for (int n = 0; n < 4; ++n) {
                    int col = col0 + wn + n * 16 + lr;
                    Cout[(size_t)grow * N + col] = acc[m][n][reg];
                }
            }
    } else {
        #pragma unroll
        for (int m = 0; m < 4; ++m)
            #pragma unroll
            for (int reg = 0; reg < 4; ++reg) {
                int grow = row0 + wm + m * 16 + lg * 4 + reg;
                int pos = grow & 2047;
                int bb = grow >> 11;
                #pragma unroll
                for (int n = 0; n < 4; ++n) {
                    int col = col0 + wn + n * 16 + lr;
                    int part = col >> 10;           // 0=q 1=k 2=v
                    int h = (col >> 6) & 15;
                    int d = col & 63;               // = n*16 + lr (64-aligned head tiles)
                    float v0 = acc[m][n][reg];
                    size_t base = (((size_t)bb * 16 + h) * 2048 + pos) * 64;
                    if (part == 2) {
                        vb[base + d] = f2bf(v0);
                    } else if (n < 2) {             // d < 32; partner at n+2 (d+32), same lane
                        float v1 = acc[m][n + 2][reg];
                        float inv = expf(-0.28782313662f * (float)d);  // 10000^(-d/32)
                        float ang = (float)pos * inv;
                        float s, c;
                        sincosf(ang, &s, &c);
                        unsigned short* dst = (part == 0) ? qb : kb;
                        dst[base + d]      = f2bf(v0 * c - v1 * s);
                        dst[base + d + 32] = f2bf(v1 * c + v0 * s);
                    }
                }
            }
    }
}

// Flash attention: one block per (q-tile of 64 rows, b*16+h). 4 waves, each owns 16 q rows.
__global__ __launch_bounds__(256) void attn_kernel(
    const unsigned short* __restrict__ qbuf, const unsigned short* __restrict__ kbuf,
    const unsigned short* __restrict__ vbuf, const int* __restrict__ mask,
    unsigned short* __restrict__ obuf)
{
    __shared__ __align__(16) unsigned short Ks[64][72];   // [kv][d]
    __shared__ __align__(16) unsigned short Vs[64][72];   // [d][kv]  (transposed)
    __shared__ __align__(16) unsigned short Ps[4][16][72];
    __shared__ int Ms[64];

    int qt = blockIdx.x, bh = blockIdx.y;
    int b = bh >> 4, h = bh & 15;
    int tid = threadIdx.x, wid = tid >> 6, lane = tid & 63, lr = lane & 15, lg = lane >> 4;
    int qrow0 = qt * 64 + wid * 16;
    const size_t bhbase = (size_t)bh * 2048 * 64;

    bf16x8 qf[2];
    #pragma unroll
    for (int kk = 0; kk < 2; ++kk)
        qf[kk] = *(const bf16x8*)(qbuf + bhbase + (size_t)(qrow0 + lr) * 64 + kk * 32 + lg * 8);

    f32x4 oacc[4];
    for (int n = 0; n < 4; ++n)
        for (int i = 0; i < 4; ++i) oacc[n][i] = 0.0f;
    float mrow[4] = {-INFINITY, -INFINITY, -INFINITY, -INFINITY};
    float lrow[4] = {0.f, 0.f, 0.f, 0.f};

    for (int kv0 = 0; kv0 < 2048; kv0 += 64) {
        // stage K (natural) and V (transposed)
        #pragma unroll
        for (int i = 0; i < 2; ++i) {
            int idx = tid + 256 * i;              // 0..511
            int r = idx >> 3, c = (idx & 7) * 8;
            *(float4*)(&Ks[r][c]) = *(const float4*)(kbuf + bhbase + (size_t)(kv0 + r) * 64 + c);
            float4 vv = *(const float4*)(vbuf + bhbase + (size_t)(kv0 + r) * 64 + c);
            unsigned short* vp = (unsigned short*)&vv;
            #pragma unroll
            for (int j = 0; j < 8; ++j) Vs[c + j][r] = vp[j];
        }
        if (tid < 64) Ms[tid] = mask[b * 2048 + kv0 + tid];
        __syncthreads();

        // S = (Q K^T) * scale
        f32x4 sacc[4];
        for (int n = 0; n < 4; ++n)
            for (int i = 0; i < 4; ++i) sacc[n][i] = 0.0f;
        #pragma unroll
        for (int kk = 0; kk < 2; ++kk)
            #pragma unroll
            for (int n = 0; n < 4; ++n) {
                bf16x8 kf = *(const bf16x8*)(&Ks[n * 16 + lr][kk * 32 + lg * 8]);
                sacc[n] = __builtin_amdgcn_mfma_f32_16x16x32_bf16(qf[kk], kf, sacc[n], 0, 0, 0);
            }

        float sv[4][4], tmax[4];
        #pragma unroll
        for (int reg = 0; reg < 4; ++reg) tmax[reg] = -INFINITY;
        #pragma unroll
        for (int n = 0; n < 4; ++n) {
            bool live = (Ms[n * 16 + lr] != 0);
            #pragma unroll
            for (int reg = 0; reg < 4; ++reg) {
                float s = live ? sacc[n][reg] * 0.125f : -1e30f;
                sv[n][reg] = s;
                tmax[reg] = fmaxf(tmax[reg], s);
            }
        }
        #pragma unroll
        for (int off = 1; off < 16; off <<= 1)
            #pragma unroll
            for (int reg = 0; reg < 4; ++reg)
                tmax[reg] = fmaxf(tmax[reg], __shfl_xor(tmax[reg], off));

        float mnew[4], psum[4];
        #pragma unroll
        for (int reg = 0; reg < 4; ++reg) {
            mnew[reg] = fmaxf(mrow[reg], tmax[reg]);
            float sc = (mrow[reg] == -INFINITY) ? 0.f : __expf(mrow[reg] - mnew[reg]);
            lrow[reg] *= sc;
            #pragma unroll
            for (int n = 0; n < 4; ++n) oacc[n][reg] *= sc;   // per-row component only
            mrow[reg] = mnew[reg];
            psum[reg] = 0.f;
        }
        #pragma unroll
        for (int n = 0; n < 4; ++n)
            #pragma unroll
            for (int reg = 0; reg < 4; ++reg) {
                float p = __expf(sv[n][reg] - mnew[reg]);
                psum[reg] += p;
                Ps[wid][lg * 4 + reg][n * 16 + lr] = f2bf(p);
            }
        #pragma unroll
        for (int off = 1; off < 16; off <<= 1)
            #pragma unroll
            for (int reg = 0; reg < 4; ++reg)
                psum[reg] += __shfl_xor(psum[reg], off);
        #pragma unroll
        for (int reg = 0; reg < 4; ++reg) lrow[reg] += psum[reg];

        // O += P V   (P via per-wave LDS re-layout; V^T gives contiguous B-frags)
        #pragma unroll
        for (int kk = 0; kk < 2; ++kk) {
            bf16x8 pf = *(const bf16x8*)(&Ps[wid][lr][kk * 32 + lg * 8]);
            #pragma unroll
            for (int n = 0; n < 4; ++n) {
                bf16x8 vf = *(const bf16x8*)(&Vs[n * 16 + lr][kk * 32 + lg * 8]);
                oacc[n] = __builtin_amdgcn_mfma_f32_16x16x32_bf16(pf, vf, oacc[n], 0, 0, 0);
            }
        }
        __syncthreads();
    }

    #pragma unroll
    for (int reg = 0; reg < 4; ++reg) {
        int qrow = qrow0 + lg * 4 + reg;
        float linv = 1.0f / lrow[reg];
        #pragma unroll
        for (int n = 0; n < 4; ++n)
            obuf[((size_t)b * 2048 + qrow) * 1024 + h * 64 + n * 16 + lr] = f2bf(oacc[n][reg] * linv);
    }
}

extern "C" void kernel_launch(void* const* d_in, const int* in_sizes, int n_in,
                              void* d_out, int out_size, void* d_ws, size_t ws_size,
                              hipStream_t stream) {
    const float* x      = (const float*)d_in[0];
    const int* key_mask = (const int*)d_in[1];
    const float* w_qkv  = (const float*)d_in[2];
    const float* w_proj = (const float*)d_in[3];
    float* out = (float*)d_out;

    // ws layout (bf16): q | k | v  ([B,H,L,Dh] = 4194304 each), attn_out ([B,L,D])
    unsigned short* ws = (unsigned short*)d_ws;
    unsigned short* qb = ws;
    unsigned short* kb = ws + (size_t)4194304;
    unsigned short* vb = ws + (size_t)2 * 4194304;
    unsigned short* ob = ws + (size_t)3 * 4194304;

    dim3 blk(256);
    // qkv GEMM + RoPE: M=4096, N=3072, K=1024
    gemm_kernel<0><<<dim3(24, 32), blk, 0, stream>>>(x, w_qkv, qb, kb, vb, nullptr, 4096, 3072, 1024);
    // flash attention: 32 q-tiles x 32 (b,h)
    attn_kernel<<<dim3(32, 32), blk, 0, stream>>>(qb, kb, vb, key_mask, ob);
    // proj GEMM: M=4096, N=1024, K=1024
    gemm_kernel<1><<<dim3(8, 32), blk, 0, stream>>>(ob, w_proj, nullptr, nullptr, nullptr, out, 4096, 1024, 1024);
}

// Round 3
// 319.419 us; speedup vs baseline: 1.1160x; 1.1160x over previous
//
#include <hip/hip_runtime.h>
#include <hip/hip_bf16.h>
#include <math.h>

// B=2, L=2048, D=1024, H=16, Dh=64. M = B*L = 4096.
// Pipeline: gemm<0> (x @ w_qkv + RoPE -> q,k bf16 [B,H,L,Dh]; v bf16 TRANSPOSED [B,H,Dh,L])
//           attn    (flash attention, no K/V LDS staging -> attn_out bf16 [B,L,D])
//           gemm<1> (attn_out @ w_proj -> f32 d_out)

#define BM 128
#define BN 128
#define BK 32
#define LDK 40   // padded LDS row stride in bf16 elems (80B, 16B-aligned rows)

typedef __attribute__((ext_vector_type(8))) short bf16x8;
typedef __attribute__((ext_vector_type(4))) float f32x4;

__device__ __forceinline__ unsigned short f2bf(float f) {
    union { float f; unsigned int u; } v; v.f = f;
    unsigned int u = v.u;
    return (unsigned short)((u + 0x7FFFu + ((u >> 16) & 1u)) >> 16);
}

// MODE 0: A = f32 x[M,K], B = f32 w_qkv[K, N=3072]; epilogue: RoPE, scatter q/k [bh][L][64], v^T [bh][64][L]
// MODE 1: A = bf16 attn_out[M,K], B = f32 w_proj[K,N]; epilogue: f32 C[M,N]
template<int MODE>
__global__ __launch_bounds__(256) void gemm_kernel(
    const void* __restrict__ Aptr, const float* __restrict__ Bptr,
    unsigned short* __restrict__ qb, unsigned short* __restrict__ kb,
    unsigned short* __restrict__ vb, float* __restrict__ Cout,
    int M, int N, int K)
{
    __shared__ __align__(16) unsigned short As[BM][LDK];
    __shared__ __align__(16) unsigned short Bs[BN][LDK];
    int tid = threadIdx.x;
    int wid = tid >> 6, lane = tid & 63, lr = lane & 15, lg = lane >> 4;
    int wm = (wid >> 1) * 64, wn = (wid & 1) * 64;
    int row0 = blockIdx.y * BM, col0 = blockIdx.x * BN;

    f32x4 acc[4][4];
    for (int m = 0; m < 4; ++m)
        for (int n = 0; n < 4; ++n)
            for (int i = 0; i < 4; ++i) acc[m][n][i] = 0.0f;

    for (int k0 = 0; k0 < K; k0 += BK) {
        // ---- stage A tile [BM][BK] as bf16, k-contiguous ----
        if (MODE == 0) {
            const float* A = (const float*)Aptr;
            #pragma unroll
            for (int i = 0; i < 4; ++i) {
                int idx = tid + 256 * i;          // 0..1023
                int r = idx >> 3, c = (idx & 7) * 4;
                float4 f = *(const float4*)(A + (size_t)(row0 + r) * K + k0 + c);
                ushort4 hh;
                hh.x = f2bf(f.x); hh.y = f2bf(f.y); hh.z = f2bf(f.z); hh.w = f2bf(f.w);
                *(ushort4*)(&As[r][c]) = hh;
            }
        } else {
            const unsigned short* A = (const unsigned short*)Aptr;
            #pragma unroll
            for (int i = 0; i < 2; ++i) {
                int idx = tid + 256 * i;          // 0..511
                int r = idx >> 2, c = (idx & 3) * 8;
                *(float4*)(&As[r][c]) = *(const float4*)(A + (size_t)(row0 + r) * K + k0 + c);
            }
        }
        // ---- stage B tile transposed: Bs[n][k] (B^T layout) ----
        #pragma unroll
        for (int i = 0; i < 4; ++i) {
            int idx = tid + 256 * i;              // 0..1023
            int kk = idx >> 5, c = (idx & 31) * 4;
            float4 f = *(const float4*)(Bptr + (size_t)(k0 + kk) * N + col0 + c);
            Bs[c + 0][kk] = f2bf(f.x);
            Bs[c + 1][kk] = f2bf(f.y);
            Bs[c + 2][kk] = f2bf(f.z);
            Bs[c + 3][kk] = f2bf(f.w);
        }
        __syncthreads();

        bf16x8 af[4], bfr[4];
        #pragma unroll
        for (int m = 0; m < 4; ++m) af[m] = *(const bf16x8*)(&As[wm + m * 16 + lr][lg * 8]);
        #pragma unroll
        for (int n = 0; n < 4; ++n) bfr[n] = *(const bf16x8*)(&Bs[wn + n * 16 + lr][lg * 8]);
        #pragma unroll
        for (int m = 0; m < 4; ++m)
            #pragma unroll
            for (int n = 0; n < 4; ++n)
                acc[m][n] = __builtin_amdgcn_mfma_f32_16x16x32_bf16(af[m], bfr[n], acc[m][n], 0, 0, 0);
        __syncthreads();
    }

    // ---- epilogue ----
    if (MODE == 1) {
        #pragma unroll
        for (int m = 0; m < 4; ++m)
            #pragma unroll
            for (int reg = 0; reg < 4; ++reg) {
                int grow = row0 + wm + m * 16 + lg * 4 + reg;
                #pragma unroll
                for (int n = 0; n < 4; ++n) {
                    int col = col0 + wn + n * 16 + lr;
                    Cout[(size_t)grow * N + col] = acc[m][n][reg];
                }
            }
    } else {
        #pragma unroll
        for (int m = 0; m < 4; ++m)
            #pragma unroll
            for (int reg = 0; reg < 4; ++reg) {
                int grow = row0 + wm + m * 16 + lg * 4 + reg;
                int pos = grow & 2047;
                int bb = grow >> 11;
                #pragma unroll
                for (int n = 0; n < 4; ++n) {
                    int col = col0 + wn + n * 16 + lr;
                    int part = col >> 10;           // 0=q 1=k 2=v
                    int h = (col >> 6) & 15;
                    int d = col & 63;               // = n*16 + lr (64-aligned head tiles)
                    float v0 = acc[m][n][reg];
                    if (part == 2) {
                        // v stored TRANSPOSED: [bh][d][kv=pos]
                        vb[((size_t)bb * 16 + h) * 131072 + (size_t)d * 2048 + pos] = f2bf(v0);
                    } else if (n < 2) {             // d < 32; partner at n+2 (d+32), same lane
                        float v1 = acc[m][n + 2][reg];
                        float inv = expf(-0.28782313662f * (float)d);  // 10000^(-d/32)
                        float ang = (float)pos * inv;
                        float s, c;
                        sincosf(ang, &s, &c);
                        unsigned short* dst = (part == 0) ? qb : kb;
                        size_t base = (((size_t)bb * 16 + h) * 2048 + pos) * 64;
                        dst[base + d]      = f2bf(v0 * c - v1 * s);
                        dst[base + d + 32] = f2bf(v1 * c + v0 * s);
                    }
                }
            }
    }
}

// Flash attention v2: no K/V LDS staging (L2-resident), no barriers.
// One block = 4 waves; each wave owns 32 q-rows. Block covers 128 q-rows of one (b,h).
__global__ __launch_bounds__(256) void attn_kernel(
    const unsigned short* __restrict__ qbuf, const unsigned short* __restrict__ kbuf,
    const unsigned short* __restrict__ vtbuf, const int* __restrict__ mask,
    unsigned short* __restrict__ obuf)
{
    __shared__ __align__(16) unsigned short Ps[4][32][72];  // per-wave P bounce

    int qt = blockIdx.x, bh = blockIdx.y;
    int b = bh >> 4, h = bh & 15;
    int tid = threadIdx.x, wid = tid >> 6, lane = tid & 63, lr = lane & 15, lg = lane >> 4;
    int qrow0 = qt * 128 + wid * 32;
    const size_t bhbase = (size_t)bh * (2048 * 64);
    const unsigned short* vt = vtbuf + bhbase;   // [64][2048]
    const int* mptr = mask + b * 2048;

    bf16x8 qf[2][2];
    #pragma unroll
    for (int r2 = 0; r2 < 2; ++r2)
        #pragma unroll
        for (int kk = 0; kk < 2; ++kk)
            qf[r2][kk] = *(const bf16x8*)(qbuf + bhbase + (size_t)(qrow0 + r2 * 16 + lr) * 64 + kk * 32 + lg * 8);

    f32x4 oacc[2][4];
    #pragma unroll
    for (int r2 = 0; r2 < 2; ++r2)
        #pragma unroll
        for (int n = 0; n < 4; ++n)
            #pragma unroll
            for (int i = 0; i < 4; ++i) oacc[r2][n][i] = 0.0f;
    float mrow[2][4], lrow[2][4];
    #pragma unroll
    for (int r2 = 0; r2 < 2; ++r2)
        #pragma unroll
        for (int reg = 0; reg < 4; ++reg) { mrow[r2][reg] = -INFINITY; lrow[r2][reg] = 0.f; }

    for (int kv0 = 0; kv0 < 2048; kv0 += 64) {
        // K fragments direct from global (L1/L2-hot)
        bf16x8 kf[2][4];
        #pragma unroll
        for (int kk = 0; kk < 2; ++kk)
            #pragma unroll
            for (int n = 0; n < 4; ++n)
                kf[kk][n] = *(const bf16x8*)(kbuf + bhbase + (size_t)(kv0 + n * 16 + lr) * 64 + kk * 32 + lg * 8);
        int live[4];
        #pragma unroll
        for (int n = 0; n < 4; ++n) live[n] = mptr[kv0 + n * 16 + lr];

        // S = Q K^T
        f32x4 sacc[2][4];
        #pragma unroll
        for (int r2 = 0; r2 < 2; ++r2)
            #pragma unroll
            for (int n = 0; n < 4; ++n)
                #pragma unroll
                for (int i = 0; i < 4; ++i) sacc[r2][n][i] = 0.0f;
        #pragma unroll
        for (int kk = 0; kk < 2; ++kk)
            #pragma unroll
            for (int r2 = 0; r2 < 2; ++r2)
                #pragma unroll
                for (int n = 0; n < 4; ++n)
                    sacc[r2][n] = __builtin_amdgcn_mfma_f32_16x16x32_bf16(qf[r2][kk], kf[kk][n], sacc[r2][n], 0, 0, 0);

        // scale + mask + row max (rows live in lg*4+reg; reduce over 16 lanes)
        float tmax[2][4];
        #pragma unroll
        for (int r2 = 0; r2 < 2; ++r2)
            #pragma unroll
            for (int reg = 0; reg < 4; ++reg) tmax[r2][reg] = -INFINITY;
        #pragma unroll
        for (int r2 = 0; r2 < 2; ++r2)
            #pragma unroll
            for (int n = 0; n < 4; ++n)
                #pragma unroll
                for (int reg = 0; reg < 4; ++reg) {
                    float s = live[n] ? sacc[r2][n][reg] * 0.125f : -1e30f;
                    sacc[r2][n][reg] = s;
                    tmax[r2][reg] = fmaxf(tmax[r2][reg], s);
                }
        #pragma unroll
        for (int off = 1; off < 16; off <<= 1)
            #pragma unroll
            for (int r2 = 0; r2 < 2; ++r2)
                #pragma unroll
                for (int reg = 0; reg < 4; ++reg)
                    tmax[r2][reg] = fmaxf(tmax[r2][reg], __shfl_xor(tmax[r2][reg], off));

        #pragma unroll
        for (int r2 = 0; r2 < 2; ++r2)
            #pragma unroll
            for (int reg = 0; reg < 4; ++reg) {
                float mnew = fmaxf(mrow[r2][reg], tmax[r2][reg]);
                float sc = (mrow[r2][reg] == -INFINITY) ? 0.f : __expf(mrow[r2][reg] - mnew);
                lrow[r2][reg] *= sc;
                #pragma unroll
                for (int n = 0; n < 4; ++n) oacc[r2][n][reg] *= sc;
                mrow[r2][reg] = mnew;
            }
        float psum[2][4];
        #pragma unroll
        for (int r2 = 0; r2 < 2; ++r2)
            #pragma unroll
            for (int reg = 0; reg < 4; ++reg) psum[r2][reg] = 0.f;
        #pragma unroll
        for (int r2 = 0; r2 < 2; ++r2)
            #pragma unroll
            for (int n = 0; n < 4; ++n)
                #pragma unroll
                for (int reg = 0; reg < 4; ++reg) {
                    float p = __expf(sacc[r2][n][reg] - mrow[r2][reg]);
                    psum[r2][reg] += p;
                    Ps[wid][r2 * 16 + lg * 4 + reg][n * 16 + lr] = f2bf(p);
                }
        #pragma unroll
        for (int off = 1; off < 16; off <<= 1)
            #pragma unroll
            for (int r2 = 0; r2 < 2; ++r2)
                #pragma unroll
                for (int reg = 0; reg < 4; ++reg)
                    psum[r2][reg] += __shfl_xor(psum[r2][reg], off);
        #pragma unroll
        for (int r2 = 0; r2 < 2; ++r2)
            #pragma unroll
            for (int reg = 0; reg < 4; ++reg) lrow[r2][reg] += psum[r2][reg];

        // V fragments direct from v^T global; P fragments from per-wave LDS bounce
        bf16x8 vf[2][4];
        #pragma unroll
        for (int kk = 0; kk < 2; ++kk)
            #pragma unroll
            for (int n = 0; n < 4; ++n)
                vf[kk][n] = *(const bf16x8*)(vt + (size_t)(n * 16 + lr) * 2048 + kv0 + kk * 32 + lg * 8);
        bf16x8 pf[2][2];
        #pragma unroll
        for (int r2 = 0; r2 < 2; ++r2)
            #pragma unroll
            for (int kk = 0; kk < 2; ++kk)
                pf[r2][kk] = *(const bf16x8*)(&Ps[wid][r2 * 16 + lr][kk * 32 + lg * 8]);
        #pragma unroll
        for (int kk = 0; kk < 2; ++kk)
            #pragma unroll
            for (int r2 = 0; r2 < 2; ++r2)
                #pragma unroll
                for (int n = 0; n < 4; ++n)
                    oacc[r2][n] = __builtin_amdgcn_mfma_f32_16x16x32_bf16(pf[r2][kk], vf[kk][n], oacc[r2][n], 0, 0, 0);
    }

    #pragma unroll
    for (int r2 = 0; r2 < 2; ++r2)
        #pragma unroll
        for (int reg = 0; reg < 4; ++reg) {
            int qrow = qrow0 + r2 * 16 + lg * 4 + reg;
            float linv = 1.0f / lrow[r2][reg];
            #pragma unroll
            for (int n = 0; n < 4; ++n)
                obuf[((size_t)b * 2048 + qrow) * 1024 + h * 64 + n * 16 + lr] = f2bf(oacc[r2][n][reg] * linv);
        }
}

extern "C" void kernel_launch(void* const* d_in, const int* in_sizes, int n_in,
                              void* d_out, int out_size, void* d_ws, size_t ws_size,
                              hipStream_t stream) {
    const float* x      = (const float*)d_in[0];
    const int* key_mask = (const int*)d_in[1];
    const float* w_qkv  = (const float*)d_in[2];
    const float* w_proj = (const float*)d_in[3];
    float* out = (float*)d_out;

    // ws layout (bf16): q [bh][L][64] | k [bh][L][64] | v^T [bh][64][L] | attn_out [B,L,D]
    unsigned short* ws = (unsigned short*)d_ws;
    unsigned short* qb = ws;
    unsigned short* kb = ws + (size_t)4194304;
    unsigned short* vb = ws + (size_t)2 * 4194304;
    unsigned short* ob = ws + (size_t)3 * 4194304;

    dim3 blk(256);
    // qkv GEMM + RoPE: M=4096, N=3072, K=1024
    gemm_kernel<0><<<dim3(24, 32), blk, 0, stream>>>(x, w_qkv, qb, kb, vb, nullptr, 4096, 3072, 1024);
    // flash attention: 16 q-tiles (128 rows) x 32 (b,h)
    attn_kernel<<<dim3(16, 32), blk, 0, stream>>>(qb, kb, vb, key_mask, ob);
    // proj GEMM: M=4096, N=1024, K=1024
    gemm_kernel<1><<<dim3(8, 32), blk, 0, stream>>>(ob, w_proj, nullptr, nullptr, nullptr, out, 4096, 1024, 1024);
}

// Round 4
// 236.557 us; speedup vs baseline: 1.5070x; 1.3503x over previous
//
#include <hip/hip_runtime.h>
#include <hip/hip_bf16.h>
#include <math.h>

// B=2, L=2048, D=1024, H=16, Dh=64. M = B*L = 4096.
// prep:    w_qkv -> bf16 wqT [3072][1024], w_proj -> bf16 wpT [1024][1024], rope table [2048][32]
// gemm<0>: x(f32) @ wqT + RoPE -> q,k bf16 [bh][L][64]; v bf16 TRANSPOSED [bh][64][L]
// attn:    flash attention (K/V direct from L2, prefetched) -> ob bf16 [B,L,D]
// gemm<1>: ob(bf16) @ wpT -> f32 d_out

typedef __attribute__((ext_vector_type(8))) short bf16x8;
typedef __attribute__((ext_vector_type(4))) float f32x4;

__device__ __forceinline__ unsigned short f2bf(float f) {
    union { float f; unsigned int u; } v; v.f = f;
    unsigned int u = v.u;
    return (unsigned short)((u + 0x7FFFu + ((u >> 16) & 1u)) >> 16);
}

__device__ __forceinline__ void gload_lds16(const unsigned short* g, unsigned short* l) {
    __builtin_amdgcn_global_load_lds(
        (const __attribute__((address_space(1))) void*)g,
        (__attribute__((address_space(3))) void*)l, 16, 0, 0);
}

// ---- prep: transpose f32 [1024][Ncols] -> bf16 [Ncols][1024] ----
__global__ __launch_bounds__(256) void prep_wT(const float* __restrict__ w,
                                               unsigned short* __restrict__ wT, int Ncols)
{
    __shared__ unsigned short t[32][34];
    int tid = threadIdx.x;
    int n0 = blockIdx.x * 32, k0 = blockIdx.y * 32;
    int r = tid >> 3, c4 = (tid & 7) * 4;
    float4 f = *(const float4*)(w + (size_t)(k0 + r) * Ncols + n0 + c4);
    t[c4 + 0][r] = f2bf(f.x);
    t[c4 + 1][r] = f2bf(f.y);
    t[c4 + 2][r] = f2bf(f.z);
    t[c4 + 3][r] = f2bf(f.w);
    __syncthreads();
    ushort4 o;
    o.x = t[r][c4]; o.y = t[r][c4 + 1]; o.z = t[r][c4 + 2]; o.w = t[r][c4 + 3];
    *(ushort4*)(wT + (size_t)(n0 + r) * 1024 + k0 + c4) = o;
}

// ---- prep: rope table tab[pos][d] = (cos, sin), pos<2048, d<32 ----
__global__ __launch_bounds__(256) void prep_rope(float2* __restrict__ tab)
{
    int i = blockIdx.x * 256 + threadIdx.x;        // 65536
    int pos = i >> 5, d = i & 31;
    float inv = expf(-0.28782313662f * (float)d);  // 10000^(-d/32)
    float ang = (float)pos * inv;
    float s, c;
    sincosf(ang, &s, &c);
    tab[i] = make_float2(c, s);
}

// ---- main GEMM, m97 structure: 128x128 tile, BK=64, global_load_lds B (and A in MODE1) ----
// MODE 0: A f32 x [4096][1024]; epilogue RoPE scatter q/k + v^T
// MODE 1: A bf16 ob [4096][1024]; epilogue f32 C
template<int MODE>
__global__ __launch_bounds__(256) void gemm_kernel(
    const void* __restrict__ Aptr, const unsigned short* __restrict__ BT,
    const float2* __restrict__ ropetab,
    unsigned short* __restrict__ qb, unsigned short* __restrict__ kb,
    unsigned short* __restrict__ vb, float* __restrict__ Cout, int N)
{
    const int K = 1024;
    __shared__ __align__(16) unsigned short As[128 * 64];
    __shared__ __align__(16) unsigned short Bs[128 * 64];
    int tid = threadIdx.x;
    int wid = tid >> 6, lane = tid & 63, lr = lane & 15, lg = lane >> 4;
    int wm = (wid >> 1) * 64, wn = (wid & 1) * 64;
    int row0 = blockIdx.y * 128, col0 = blockIdx.x * 128;

    f32x4 acc[4][4];
    #pragma unroll
    for (int m = 0; m < 4; ++m)
        #pragma unroll
        for (int n = 0; n < 4; ++n)
            #pragma unroll
            for (int i = 0; i < 4; ++i) acc[m][n][i] = 0.0f;

    for (int k0 = 0; k0 < K; k0 += 64) {
        // B tile: 128 rows(out-col) x 64 k, bf16, linear LDS, async 16B loads
        #pragma unroll
        for (int i = 0; i < 4; ++i) {
            int cbase = (i * 4 + wid) * 64;
            int c = cbase + lane;
            int r = c >> 3, cc = (c & 7) * 8;
            gload_lds16(BT + (size_t)(col0 + r) * K + k0 + cc, Bs + cbase * 8);
        }
        // A tile
        if (MODE == 0) {
            const float* A = (const float*)Aptr;
            #pragma unroll
            for (int i = 0; i < 8; ++i) {
                int c = tid + i * 256;            // 0..2047 float4 chunks
                int r = c >> 4, cf = (c & 15) * 4;
                float4 f = *(const float4*)(A + (size_t)(row0 + r) * K + k0 + cf);
                ushort4 hh;
                hh.x = f2bf(f.x); hh.y = f2bf(f.y); hh.z = f2bf(f.z); hh.w = f2bf(f.w);
                *(ushort4*)(&As[r * 64 + cf]) = hh;
            }
        } else {
            const unsigned short* A = (const unsigned short*)Aptr;
            #pragma unroll
            for (int i = 0; i < 4; ++i) {
                int cbase = (i * 4 + wid) * 64;
                int c = cbase + lane;
                int r = c >> 3, cc = (c & 7) * 8;
                gload_lds16(A + (size_t)(row0 + r) * K + k0 + cc, As + cbase * 8);
            }
        }
        __syncthreads();
        #pragma unroll
        for (int kk = 0; kk < 2; ++kk) {
            bf16x8 af[4], bfr[4];
            #pragma unroll
            for (int m = 0; m < 4; ++m)
                af[m] = *(const bf16x8*)(&As[(wm + m * 16 + lr) * 64 + kk * 32 + lg * 8]);
            #pragma unroll
            for (int n = 0; n < 4; ++n)
                bfr[n] = *(const bf16x8*)(&Bs[(wn + n * 16 + lr) * 64 + kk * 32 + lg * 8]);
            #pragma unroll
            for (int m = 0; m < 4; ++m)
                #pragma unroll
                for (int n = 0; n < 4; ++n)
                    acc[m][n] = __builtin_amdgcn_mfma_f32_16x16x32_bf16(af[m], bfr[n], acc[m][n], 0, 0, 0);
        }
        __syncthreads();
    }

    if (MODE == 1) {
        #pragma unroll
        for (int m = 0; m < 4; ++m)
            #pragma unroll
            for (int reg = 0; reg < 4; ++reg) {
                int grow = row0 + wm + m * 16 + lg * 4 + reg;
                #pragma unroll
                for (int n = 0; n < 4; ++n)
                    Cout[(size_t)grow * N + col0 + wn + n * 16 + lr] = acc[m][n][reg];
            }
    } else {
        #pragma unroll
        for (int m = 0; m < 4; ++m)
            #pragma unroll
            for (int reg = 0; reg < 4; ++reg) {
                int grow = row0 + wm + m * 16 + lg * 4 + reg;
                int pos = grow & 2047;
                int bb = grow >> 11;
                #pragma unroll
                for (int n = 0; n < 4; ++n) {
                    int col = col0 + wn + n * 16 + lr;
                    int part = col >> 10;           // 0=q 1=k 2=v
                    int h = (col >> 6) & 15;
                    int d = col & 63;
                    float v0 = acc[m][n][reg];
                    if (part == 2) {
                        vb[((size_t)bb * 16 + h) * 131072 + (size_t)d * 2048 + pos] = f2bf(v0);
                    } else if (n < 2) {             // d<32, partner at n+2 (d+32) same lane
                        float v1 = acc[m][n + 2][reg];
                        float2 cs = ropetab[pos * 32 + d];
                        unsigned short* dst = (part == 0) ? qb : kb;
                        size_t base = (((size_t)bb * 16 + h) * 2048 + pos) * 64;
                        dst[base + d]      = f2bf(v0 * cs.x - v1 * cs.y);
                        dst[base + d + 32] = f2bf(v1 * cs.x + v0 * cs.y);
                    }
                }
            }
    }
}

// ---- flash attention: 4 waves x 32 q-rows, K/V direct from global, prefetched ----
__global__ __launch_bounds__(256, 1) void attn_kernel(
    const unsigned short* __restrict__ qbuf, const unsigned short* __restrict__ kbuf,
    const unsigned short* __restrict__ vtbuf, const int* __restrict__ mask,
    unsigned short* __restrict__ obuf)
{
    __shared__ __align__(16) unsigned short Ps[4][32][72];

    int qt = blockIdx.x, bh = blockIdx.y;
    int b = bh >> 4, h = bh & 15;
    int tid = threadIdx.x, wid = tid >> 6, lane = tid & 63, lr = lane & 15, lg = lane >> 4;
    int qrow0 = qt * 128 + wid * 32;
    const size_t bhbase = (size_t)bh * (2048 * 64);
    const unsigned short* vt = vtbuf + bhbase;   // [64][2048]
    const int* mptr = mask + b * 2048;

    bf16x8 qf[2][2];
    #pragma unroll
    for (int r2 = 0; r2 < 2; ++r2)
        #pragma unroll
        for (int kk = 0; kk < 2; ++kk)
            qf[r2][kk] = *(const bf16x8*)(qbuf + bhbase + (size_t)(qrow0 + r2 * 16 + lr) * 64 + kk * 32 + lg * 8);

    f32x4 oacc[2][4];
    #pragma unroll
    for (int r2 = 0; r2 < 2; ++r2)
        #pragma unroll
        for (int n = 0; n < 4; ++n)
            #pragma unroll
            for (int i = 0; i < 4; ++i) oacc[r2][n][i] = 0.0f;
    float mrow[2][4], lrow[2][4];
    #pragma unroll
    for (int r2 = 0; r2 < 2; ++r2)
        #pragma unroll
        for (int reg = 0; reg < 4; ++reg) { mrow[r2][reg] = -INFINITY; lrow[r2][reg] = 0.f; }

    // prologue: K(0), mask(0)
    bf16x8 kf[2][4];
    int live[4];
    #pragma unroll
    for (int kk = 0; kk < 2; ++kk)
        #pragma unroll
        for (int n = 0; n < 4; ++n)
            kf[kk][n] = *(const bf16x8*)(kbuf + bhbase + (size_t)(n * 16 + lr) * 64 + kk * 32 + lg * 8);
    #pragma unroll
    for (int n = 0; n < 4; ++n) live[n] = mptr[n * 16 + lr];

    for (int kv0 = 0; kv0 < 2048; kv0 += 64) {
        // S = Q K^T
        f32x4 sacc[2][4];
        #pragma unroll
        for (int r2 = 0; r2 < 2; ++r2)
            #pragma unroll
            for (int n = 0; n < 4; ++n)
                #pragma unroll
                for (int i = 0; i < 4; ++i) sacc[r2][n][i] = 0.0f;
        #pragma unroll
        for (int kk = 0; kk < 2; ++kk)
            #pragma unroll
            for (int r2 = 0; r2 < 2; ++r2)
                #pragma unroll
                for (int n = 0; n < 4; ++n)
                    sacc[r2][n] = __builtin_amdgcn_mfma_f32_16x16x32_bf16(qf[r2][kk], kf[kk][n], sacc[r2][n], 0, 0, 0);

        // prefetch V(t), K(t+1), mask(t+1) — hides L2 latency under softmax
        bf16x8 vf[2][4];
        #pragma unroll
        for (int kk = 0; kk < 2; ++kk)
            #pragma unroll
            for (int n = 0; n < 4; ++n)
                vf[kk][n] = *(const bf16x8*)(vt + (size_t)(n * 16 + lr) * 2048 + kv0 + kk * 32 + lg * 8);
        bf16x8 kn[2][4];
        int ln[4];
        if (kv0 + 64 < 2048) {
            #pragma unroll
            for (int kk = 0; kk < 2; ++kk)
                #pragma unroll
                for (int n = 0; n < 4; ++n)
                    kn[kk][n] = *(const bf16x8*)(kbuf + bhbase + (size_t)(kv0 + 64 + n * 16 + lr) * 64 + kk * 32 + lg * 8);
            #pragma unroll
            for (int n = 0; n < 4; ++n) ln[n] = mptr[kv0 + 64 + n * 16 + lr];
        }

        // scale + mask + row max
        float tmax[2][4];
        #pragma unroll
        for (int r2 = 0; r2 < 2; ++r2)
            #pragma unroll
            for (int reg = 0; reg < 4; ++reg) tmax[r2][reg] = -INFINITY;
        #pragma unroll
        for (int r2 = 0; r2 < 2; ++r2)
            #pragma unroll
            for (int n = 0; n < 4; ++n)
                #pragma unroll
                for (int reg = 0; reg < 4; ++reg) {
                    float s = live[n] ? sacc[r2][n][reg] * 0.125f : -1e30f;
                    sacc[r2][n][reg] = s;
                    tmax[r2][reg] = fmaxf(tmax[r2][reg], s);
                }
        #pragma unroll
        for (int off = 1; off < 16; off <<= 1)
            #pragma unroll
            for (int r2 = 0; r2 < 2; ++r2)
                #pragma unroll
                for (int reg = 0; reg < 4; ++reg)
                    tmax[r2][reg] = fmaxf(tmax[r2][reg], __shfl_xor(tmax[r2][reg], off));

        #pragma unroll
        for (int r2 = 0; r2 < 2; ++r2)
            #pragma unroll
            for (int reg = 0; reg < 4; ++reg) {
                float mnew = fmaxf(mrow[r2][reg], tmax[r2][reg]);
                float sc = (mrow[r2][reg] == -INFINITY) ? 0.f : __expf(mrow[r2][reg] - mnew);
                lrow[r2][reg] *= sc;
                #pragma unroll
                for (int n = 0; n < 4; ++n) oacc[r2][n][reg] *= sc;
                mrow[r2][reg] = mnew;
            }
        float psum[2][4];
        #pragma unroll
        for (int r2 = 0; r2 < 2; ++r2)
            #pragma unroll
            for (int reg = 0; reg < 4; ++reg) psum[r2][reg] = 0.f;
        #pragma unroll
        for (int r2 = 0; r2 < 2; ++r2)
            #pragma unroll
            for (int n = 0; n < 4; ++n)
                #pragma unroll
                for (int reg = 0; reg < 4; ++reg) {
                    float p = __expf(sacc[r2][n][reg] - mrow[r2][reg]);
                    psum[r2][reg] += p;
                    Ps[wid][r2 * 16 + lg * 4 + reg][n * 16 + lr] = f2bf(p);
                }
        #pragma unroll
        for (int off = 1; off < 16; off <<= 1)
            #pragma unroll
            for (int r2 = 0; r2 < 2; ++r2)
                #pragma unroll
                for (int reg = 0; reg < 4; ++reg)
                    psum[r2][reg] += __shfl_xor(psum[r2][reg], off);
        #pragma unroll
        for (int r2 = 0; r2 < 2; ++r2)
            #pragma unroll
            for (int reg = 0; reg < 4; ++reg) lrow[r2][reg] += psum[r2][reg];

        // O += P V
        bf16x8 pf[2][2];
        #pragma unroll
        for (int r2 = 0; r2 < 2; ++r2)
            #pragma unroll
            for (int kk = 0; kk < 2; ++kk)
                pf[r2][kk] = *(const bf16x8*)(&Ps[wid][r2 * 16 + lr][kk * 32 + lg * 8]);
        #pragma unroll
        for (int kk = 0; kk < 2; ++kk)
            #pragma unroll
            for (int r2 = 0; r2 < 2; ++r2)
                #pragma unroll
                for (int n = 0; n < 4; ++n)
                    oacc[r2][n] = __builtin_amdgcn_mfma_f32_16x16x32_bf16(pf[r2][kk], vf[kk][n], oacc[r2][n], 0, 0, 0);

        if (kv0 + 64 < 2048) {
            #pragma unroll
            for (int kk = 0; kk < 2; ++kk)
                #pragma unroll
                for (int n = 0; n < 4; ++n) kf[kk][n] = kn[kk][n];
            #pragma unroll
            for (int n = 0; n < 4; ++n) live[n] = ln[n];
        }
    }

    #pragma unroll
    for (int r2 = 0; r2 < 2; ++r2)
        #pragma unroll
        for (int reg = 0; reg < 4; ++reg) {
            int qrow = qrow0 + r2 * 16 + lg * 4 + reg;
            float linv = 1.0f / lrow[r2][reg];
            #pragma unroll
            for (int n = 0; n < 4; ++n)
                obuf[((size_t)b * 2048 + qrow) * 1024 + h * 64 + n * 16 + lr] = f2bf(oacc[r2][n][reg] * linv);
        }
}

extern "C" void kernel_launch(void* const* d_in, const int* in_sizes, int n_in,
                              void* d_out, int out_size, void* d_ws, size_t ws_size,
                              hipStream_t stream) {
    const float* x      = (const float*)d_in[0];
    const int* key_mask = (const int*)d_in[1];
    const float* w_qkv  = (const float*)d_in[2];
    const float* w_proj = (const float*)d_in[3];
    float* out = (float*)d_out;

    char* ws = (char*)d_ws;
    unsigned short* qb  = (unsigned short*)(ws);                       // 8.39 MB
    unsigned short* kb  = (unsigned short*)(ws + 8388608);             // 8.39 MB
    unsigned short* vtb = (unsigned short*)(ws + 16777216);            // 8.39 MB
    unsigned short* ob  = (unsigned short*)(ws + 25165824);            // 8.39 MB
    unsigned short* wqT = (unsigned short*)(ws + 33554432);            // 6.29 MB
    unsigned short* wpT = (unsigned short*)(ws + 39845888);            // 2.10 MB
    float2*         tab = (float2*)(ws + 41943040);                    // 0.52 MB

    dim3 blk(256);
    prep_wT<<<dim3(96, 32), blk, 0, stream>>>(w_qkv, wqT, 3072);
    prep_wT<<<dim3(32, 32), blk, 0, stream>>>(w_proj, wpT, 1024);
    prep_rope<<<dim3(256), blk, 0, stream>>>(tab);
    // qkv GEMM + RoPE: M=4096, N=3072, K=1024
    gemm_kernel<0><<<dim3(24, 32), blk, 0, stream>>>(x, wqT, tab, qb, kb, vtb, nullptr, 3072);
    // flash attention
    attn_kernel<<<dim3(16, 32), blk, 0, stream>>>(qb, kb, vtb, key_mask, ob);
    // proj GEMM: M=4096, N=1024, K=1024
    gemm_kernel<1><<<dim3(8, 32), blk, 0, stream>>>(ob, wpT, nullptr, nullptr, nullptr, nullptr, out, 1024);
}